// Round 2
// baseline (182.173 us; speedup 1.0000x reference)
//
#include <hip/hip_runtime.h>
#include <hip/hip_bf16.h>

__device__ __forceinline__ float bf2f(unsigned short u) {
    union { unsigned int i; float f; } v; v.i = ((unsigned int)u) << 16; return v.f;
}
__device__ __forceinline__ unsigned short f2bf(float f) {
    __hip_bfloat16 h = __float2bfloat16(f);
    return *reinterpret_cast<unsigned short*>(&h);
}

// ws layout (float indices)
#define WS_WQ   0          // 3 x 16384 canonical fp32 weights (wq, wk, wv)
#define WS_RH   49152      // 448
#define WS_RW   49600      // 448
#define WS_FLAG 50048      // int flag: 1 = inputs are fp32, 0 = bf16
#define WS_Q    50176      // 1048576 fp32  [b][g][pix][ci]
#define WS_K    1098752    // 1048576 fp32
#define WS_V    2147328    // 1048576 fp32

// ---------------------------------------------------------------------------
// prep: detect input dtype from wq bit patterns, convert weights + rel to fp32
// ---------------------------------------------------------------------------
__global__ __launch_bounds__(256) void prep_kernel(
    const void* __restrict__ wq, const void* __restrict__ wk,
    const void* __restrict__ wv, const void* __restrict__ rh,
    const void* __restrict__ rw, float* __restrict__ ws)
{
    __shared__ int sflag;
    const int tid = threadIdx.x;
    if (tid < 64) {
        // even-index shorts: bf16 data -> |x| <= ~1 ; fp32 data -> low mantissa
        // halves decode log-uniform up to 2^127, max over 64 >> 1000 w.h.p.
        const unsigned short* u = (const unsigned short*)wq;
        float v = fabsf(bf2f(u[tid * 2]));
        #pragma unroll
        for (int off = 32; off; off >>= 1) v = fmaxf(v, __shfl_down(v, off));
        if (tid == 0) { sflag = (v > 1000.f) ? 1 : 0; ((int*)(ws + WS_FLAG))[0] = sflag; }
    }
    __syncthreads();
    const int f = sflag;
    const void* srcs[3] = { wq, wk, wv };
    for (int m = 0; m < 3; ++m) {
        float* dst = ws + WS_WQ + m * 16384;
        if (f) {
            const float* s = (const float*)srcs[m];
            for (int i = tid; i < 16384; i += 256) dst[i] = s[i];
        } else {
            const unsigned short* s = (const unsigned short*)srcs[m];
            for (int i = tid; i < 16384; i += 256) dst[i] = bf2f(s[i]);
        }
    }
    if (f) {
        const float* s1 = (const float*)rh;
        const float* s2 = (const float*)rw;
        for (int i = tid; i < 448; i += 256) ws[WS_RH + i] = s1[i];
        for (int i = tid; i < 448; i += 256) ws[WS_RW + i] = s2[i];
    } else {
        const unsigned short* s1 = (const unsigned short*)rh;
        const unsigned short* s2 = (const unsigned short*)rw;
        for (int i = tid; i < 448; i += 256) ws[WS_RH + i] = bf2f(s1[i]);
        for (int i = tid; i < 448; i += 256) ws[WS_RW + i] = bf2f(s2[i]);
    }
}

// ---------------------------------------------------------------------------
// conv: three 1x1 convs -> Q,K,V fp32 in ws, layout [b][g][pix][ci].
// blockIdx.x = 32-pixel tile (256), blockIdx.y = 0:Q 1:K 2:V.
// Channel loop split in two 64-ch halves to fit fp32 weights in LDS.
// ---------------------------------------------------------------------------
__global__ __launch_bounds__(256) void conv1x1_kernel(
    const void* __restrict__ fmv, float* __restrict__ ws)
{
    const int sel = blockIdx.y;
    const float* W = ws + WS_WQ + sel * 16384;
    const int c0 = (sel == 0) ? 128 : 0;          // Q from fm_t1, K/V from fm_t0
    const int f = ((const int*)(ws + WS_FLAG))[0];

    __shared__ float x_s[32 * 68];                // 32 px x 64 ch (+pad)
    __shared__ float w_s[128 * 68];               // 128 out x 64 ch (+pad)

    const int tid = threadIdx.x;
    const int P0  = blockIdx.x * 32;
    const int b   = P0 >> 12;
    const int hw0 = P0 & 4095;
    const int p   = tid & 31;
    const int og  = tid >> 5;

    float acc[16];
    #pragma unroll
    for (int j = 0; j < 16; ++j) acc[j] = 0.f;

    for (int ch0 = 0; ch0 < 128; ch0 += 64) {
        #pragma unroll
        for (int k = 0; k < 8; ++k) {
            const int idx = tid + k * 256;        // 0..2047
            const int o = idx >> 4, c4 = idx & 15;
            float4 v = *(const float4*)(W + o * 128 + ch0 + c4 * 4);
            *(float4*)(&w_s[o * 68 + c4 * 4]) = v;
        }
        {
            const int c = tid >> 2, chunk = tid & 3;
            const int ch = c0 + ch0 + c;
            const size_t base = (((size_t)(b * 256 + ch)) << 12) + hw0 + chunk * 8;
            float xv[8];
            if (f) {
                const float* s = (const float*)fmv;
                float4 a = *(const float4*)(s + base);
                float4 bb = *(const float4*)(s + base + 4);
                xv[0]=a.x; xv[1]=a.y; xv[2]=a.z; xv[3]=a.w;
                xv[4]=bb.x; xv[5]=bb.y; xv[6]=bb.z; xv[7]=bb.w;
            } else {
                const unsigned short* s = (const unsigned short*)fmv;
                uint4 a = *(const uint4*)(s + base);
                const unsigned short* uu = (const unsigned short*)&a;
                #pragma unroll
                for (int k = 0; k < 8; ++k) xv[k] = bf2f(uu[k]);
            }
            #pragma unroll
            for (int k = 0; k < 8; ++k) x_s[(chunk * 8 + k) * 68 + c] = xv[k];
        }
        __syncthreads();
        #pragma unroll
        for (int c8 = 0; c8 < 8; ++c8) {
            float4 xa = *(const float4*)(&x_s[p * 68 + c8 * 8]);
            float4 xb = *(const float4*)(&x_s[p * 68 + c8 * 8 + 4]);
            #pragma unroll
            for (int j = 0; j < 16; ++j) {
                const float* wr = &w_s[(og * 16 + j) * 68 + c8 * 8];
                float4 wa = *(const float4*)wr;
                float4 wb = *(const float4*)(wr + 4);
                acc[j] += xa.x*wa.x + xa.y*wa.y + xa.z*wa.z + xa.w*wa.w
                        + xb.x*wb.x + xb.y*wb.y + xb.z*wb.z + xb.w*wb.w;
            }
        }
        __syncthreads();
    }

    float* dst = ws + ((sel == 0) ? WS_Q : (sel == 1) ? WS_K : WS_V)
               + (((size_t)(((b * 8 + og) << 12) + hw0 + p)) << 4);
    #pragma unroll
    for (int j = 0; j < 16; j += 4)
        *(float4*)(dst + j) = make_float4(acc[j], acc[j+1], acc[j+2], acc[j+3]);
}

// ---------------------------------------------------------------------------
__device__ __forceinline__ float dot16(const float* q, const float4* k4) {
    float4 a = k4[0], b = k4[1], c = k4[2], d = k4[3];
    return q[0]*a.x + q[1]*a.y + q[2]*a.z + q[3]*a.w
         + q[4]*b.x + q[5]*b.y + q[6]*b.z + q[7]*b.w
         + q[8]*c.x + q[9]*c.y + q[10]*c.z + q[11]*c.w
         + q[12]*d.x + q[13]*d.y + q[14]*d.z + q[15]*d.w;
}
__device__ __forceinline__ void axpy16(float* acc, float w, const float4* v4) {
    float4 a = v4[0], b = v4[1], c = v4[2], d = v4[3];
    acc[0]+=w*a.x; acc[1]+=w*a.y; acc[2]+=w*a.z; acc[3]+=w*a.w;
    acc[4]+=w*b.x; acc[5]+=w*b.y; acc[6]+=w*b.z; acc[7]+=w*b.w;
    acc[8]+=w*c.x; acc[9]+=w*c.y; acc[10]+=w*c.z; acc[11]+=w*c.w;
    acc[12]+=w*d.x; acc[13]+=w*d.y; acc[14]+=w*d.z; acc[15]+=w*d.w;
}

// attention: one thread per (b,g,h,w). 7x7 main window with rel bias (bias
// also at OOB, k=0 there), refine row/col 15-wide (OOB score=0, in softmax).
__global__ __launch_bounds__(256) void attn_kernel(
    const float* __restrict__ ws, void* __restrict__ outv)
{
    const int tid = threadIdx.x;
    const int w = tid & 63;
    const int h = blockIdx.x * 4 + (tid >> 6);
    const int g = blockIdx.y;
    const int b = blockIdx.z;
    const int f = ((const int*)(ws + WS_FLAG))[0];

    const size_t slab = ((size_t)(b * 8 + g)) << 16;
    const float* qptr = ws + WS_Q + slab + (size_t)(h * 64 + w) * 16;

    float qr[16];
    #pragma unroll
    for (int ci = 0; ci < 16; ++ci) qr[ci] = qptr[ci];

    float qrel[7];
    const float* rel = (g < 4) ? (ws + WS_RH + g * 112) : (ws + WS_RW + (g - 4) * 112);
    #pragma unroll
    for (int t = 0; t < 7; ++t) {
        float s = 0.f;
        #pragma unroll
        for (int ci = 0; ci < 16; ++ci) s += qr[ci] * rel[ci * 7 + t];
        qrel[t] = s;
    }

    const float4* Kp = (const float4*)(ws + WS_K + slab);
    const float4* Vp = (const float4*)(ws + WS_V + slab);

    float acc[16];
    #pragma unroll
    for (int ci = 0; ci < 16; ++ci) acc[ci] = 0.f;

    // ---- main 7x7 ----
    {
        float s[49];
        float mx = -3.4e38f;
        #pragma unroll
        for (int i = 0; i < 7; ++i) {
            #pragma unroll
            for (int j = 0; j < 7; ++j) {
                const int y = h + i - 3, x = w + j - 3;
                float d = 0.f;
                if (y >= 0 && y < 64 && x >= 0 && x < 64)
                    d = dot16(qr, Kp + (size_t)(y * 64 + x) * 4);
                d += qrel[(g < 4) ? i : j];
                s[i * 7 + j] = d;
                mx = fmaxf(mx, d);
            }
        }
        float den = 0.f;
        #pragma unroll
        for (int k = 0; k < 49; ++k) { s[k] = __expf(s[k] - mx); den += s[k]; }
        const float inv = 1.f / den;
        #pragma unroll
        for (int i = 0; i < 7; ++i) {
            #pragma unroll
            for (int j = 0; j < 7; ++j) {
                const int y = h + i - 3, x = w + j - 3;
                if (y >= 0 && y < 64 && x >= 0 && x < 64)
                    axpy16(acc, s[i * 7 + j] * inv, Vp + (size_t)(y * 64 + x) * 4);
            }
        }
    }
    // ---- refine row (w offsets) ----
    {
        float s[15];
        float mx = -3.4e38f;
        #pragma unroll
        for (int j = 0; j < 15; ++j) {
            const int x = w + j - 7;
            float d = 0.f;
            if (x >= 0 && x < 64) d = dot16(qr, Kp + (size_t)(h * 64 + x) * 4);
            s[j] = d; mx = fmaxf(mx, d);
        }
        float den = 0.f;
        #pragma unroll
        for (int j = 0; j < 15; ++j) { s[j] = __expf(s[j] - mx); den += s[j]; }
        const float inv = 1.f / den;
        #pragma unroll
        for (int j = 0; j < 15; ++j) {
            const int x = w + j - 7;
            if (x >= 0 && x < 64) axpy16(acc, s[j] * inv, Vp + (size_t)(h * 64 + x) * 4);
        }
    }
    // ---- refine col (h offsets) ----
    {
        float s[15];
        float mx = -3.4e38f;
        #pragma unroll
        for (int i = 0; i < 15; ++i) {
            const int y = h + i - 7;
            float d = 0.f;
            if (y >= 0 && y < 64) d = dot16(qr, Kp + (size_t)(y * 64 + w) * 4);
            s[i] = d; mx = fmaxf(mx, d);
        }
        float den = 0.f;
        #pragma unroll
        for (int i = 0; i < 15; ++i) { s[i] = __expf(s[i] - mx); den += s[i]; }
        const float inv = 1.f / den;
        #pragma unroll
        for (int i = 0; i < 15; ++i) {
            const int y = h + i - 7;
            if (y >= 0 && y < 64) axpy16(acc, s[i] * inv, Vp + (size_t)(y * 64 + w) * 4);
        }
    }

    // store: out[b][g*16+ci][h][w]
    const size_t obase = (((size_t)(b * 128 + g * 16)) << 12) + h * 64 + w;
    if (f) {
        float* op = (float*)outv + obase;
        #pragma unroll
        for (int ci = 0; ci < 16; ++ci) op[(size_t)ci << 12] = acc[ci];
    } else {
        unsigned short* op = (unsigned short*)outv + obase;
        #pragma unroll
        for (int ci = 0; ci < 16; ++ci) op[(size_t)ci << 12] = f2bf(acc[ci]);
    }
}

// ---------------------------------------------------------------------------
extern "C" void kernel_launch(void* const* d_in, const int* in_sizes, int n_in,
                              void* d_out, int out_size, void* d_ws, size_t ws_size,
                              hipStream_t stream) {
    (void)in_sizes; (void)n_in; (void)out_size; (void)ws_size;
    float* ws = (float*)d_ws;
    prep_kernel<<<dim3(1), dim3(256), 0, stream>>>(
        d_in[1], d_in[2], d_in[3], d_in[4], d_in[5], ws);
    conv1x1_kernel<<<dim3(256, 3, 1), dim3(256), 0, stream>>>(d_in[0], ws);
    attn_kernel<<<dim3(16, 8, 2), dim3(256), 0, stream>>>(ws, d_out);
}